// Round 6
// baseline (936.262 us; speedup 1.0000x reference)
//
#include <hip/hip_runtime.h>

// SimpleAGG: 3-hop graph aggregation, F=1.
// h'[v] = w_self[i]*h[v] + w_neigh[i]*sum_{e: dst[e]==v} h[src[e]]
//
// Round 6: agg was latency-chain-bound on random curh gathers
// (FETCH~=rec stream only; VALU 2%; occ 69%; model: 88 outstanding x 200cyc
// = 118us, matches). Raise concurrency: 512-thr blocks, SPLIT=4 (980 blocks
// ~3.8/CU -> 32 waves/CU) and 2x u32x4 recs per iteration (8 independent
// gathers in flight per thread). Everything else unchanged.

typedef unsigned u32x4 __attribute__((ext_vector_type(4)));
typedef float    f32x4 __attribute__((ext_vector_type(4)));

constexpr int BLK     = 256;
constexpr int BBITS   = 12;
constexpr int BUCKET  = 1 << BBITS;   // 4096 nodes, 16KB fp32 LDS
constexpr int NB_MAX  = 256;          // bucket ids fit u8
constexpr int SPLIT   = 4;            // agg blocks per bucket (512 thr each)
constexpr int TILE    = 8192;         // edges per bin block
constexpr int HBLOCKS = 1024;

// ---------------- fast path ----------------

__global__ void zero_u32(unsigned* __restrict__ p, int n) {
    int i = blockIdx.x * blockDim.x + threadIdx.x;
    if (i < n) p[i] = 0u;
}

__global__ void hist_kernel(const int* __restrict__ dst, int ne,
                            unsigned* __restrict__ count, int nb) {
    __shared__ unsigned hist[NB_MAX * 4];
    for (int b = threadIdx.x; b < NB_MAX * 4; b += blockDim.x) hist[b] = 0u;
    __syncthreads();
    const u32x4* dst4 = reinterpret_cast<const u32x4*>(dst);
    int nvec = ne >> 2;
    int sub = threadIdx.x & 3;
    for (int i = blockIdx.x * blockDim.x + threadIdx.x; i < nvec;
         i += gridDim.x * blockDim.x) {
        u32x4 d = __builtin_nontemporal_load(dst4 + i);
        atomicAdd(&hist[((d.x >> BBITS) << 2) | sub], 1u);
        atomicAdd(&hist[((d.y >> BBITS) << 2) | sub], 1u);
        atomicAdd(&hist[((d.z >> BBITS) << 2) | sub], 1u);
        atomicAdd(&hist[((d.w >> BBITS) << 2) | sub], 1u);
    }
    if (blockIdx.x == 0 && threadIdx.x == 0)
        for (int i = nvec << 2; i < ne; ++i)
            atomicAdd(&hist[(((unsigned)dst[i] >> BBITS) << 2)], 1u);
    __syncthreads();
    for (int b = threadIdx.x; b < nb; b += blockDim.x) {
        unsigned v = hist[b * 4] + hist[b * 4 + 1] + hist[b * 4 + 2] + hist[b * 4 + 3];
        if (v) atomicAdd(&count[b], v);
    }
}

// single block of NB_MAX threads: 16B-aligned exclusive scan of counts
__global__ void scan_kernel(const unsigned* __restrict__ count,
                            unsigned* __restrict__ offsets,
                            unsigned* __restrict__ cursor, int nb) {
    __shared__ unsigned s[NB_MAX];
    int t = threadIdx.x;
    unsigned v  = (t < nb) ? count[t] : 0u;
    unsigned pv = (v + 3u) & ~3u;        // pad region to multiple of 4 recs
    s[t] = pv;
    __syncthreads();
    for (int d = 1; d < NB_MAX; d <<= 1) {
        unsigned u = (t >= d) ? s[t - d] : 0u;
        __syncthreads();
        s[t] += u;
        __syncthreads();
    }
    unsigned excl = s[t] - pv;
    if (t < nb) { offsets[t] = excl; cursor[t] = excl; }
}

__global__ __launch_bounds__(256)
void bin_kernel(const int* __restrict__ src, const int* __restrict__ dst, int ne,
                unsigned* __restrict__ cursor, unsigned* __restrict__ recs) {
    __shared__ unsigned hist[NB_MAX];
    __shared__ unsigned start[NB_MAX];
    __shared__ unsigned lpos[NB_MAX];
    __shared__ unsigned gbase[NB_MAX];
    __shared__ unsigned rec[TILE];
    __shared__ unsigned char bid[TILE];

    int base = blockIdx.x * TILE;
    int cnt = min(TILE, ne - base);
    if (cnt <= 0) return;

    for (int b = threadIdx.x; b < NB_MAX; b += blockDim.x) hist[b] = 0u;
    __syncthreads();

    int nvec = cnt & ~3;
    const u32x4* dst4 = reinterpret_cast<const u32x4*>(dst + base);
    const u32x4* src4 = reinterpret_cast<const u32x4*>(src + base);

    // phase 1: tile histogram
    for (int i = threadIdx.x; i < (nvec >> 2); i += blockDim.x) {
        u32x4 d = dst4[i];
        atomicAdd(&hist[d.x >> BBITS], 1u);
        atomicAdd(&hist[d.y >> BBITS], 1u);
        atomicAdd(&hist[d.z >> BBITS], 1u);
        atomicAdd(&hist[d.w >> BBITS], 1u);
    }
    if (threadIdx.x == 0)
        for (int i = nvec; i < cnt; ++i)
            atomicAdd(&hist[(unsigned)dst[base + i] >> BBITS], 1u);
    __syncthreads();

    // phase 2: scan hist -> start (exclusive), reserve global runs
    {
        int t = threadIdx.x;           // blockDim == NB_MAX == 256
        unsigned v = hist[t];
        start[t] = v;
        __syncthreads();
        for (int d = 1; d < NB_MAX; d <<= 1) {
            unsigned u = (t >= d) ? start[t - d] : 0u;
            __syncthreads();
            start[t] += u;
            __syncthreads();
        }
        unsigned excl = start[t] - v;
        __syncthreads();
        start[t] = excl;
        lpos[t]  = excl;
        if (v) gbase[t] = atomicAdd(&cursor[t], v);
        __syncthreads();
    }

    // phase 3: place records into LDS sorted by bucket (NT: last read of tile)
    for (int i = threadIdx.x; i < (nvec >> 2); i += blockDim.x) {
        u32x4 d = __builtin_nontemporal_load(dst4 + i);
        u32x4 s = __builtin_nontemporal_load(src4 + i);
        unsigned dd[4] = {d.x, d.y, d.z, d.w};
        unsigned ss[4] = {s.x, s.y, s.z, s.w};
#pragma unroll
        for (int k = 0; k < 4; ++k) {
            unsigned b = dd[k] >> BBITS;
            unsigned p = atomicAdd(&lpos[b], 1u);
            rec[p] = ((dd[k] & (BUCKET - 1)) << 20) | ss[k];
            bid[p] = (unsigned char)b;
        }
    }
    if (threadIdx.x == 0)
        for (int i = nvec; i < cnt; ++i) {
            unsigned dd = (unsigned)dst[base + i], ss = (unsigned)src[base + i];
            unsigned b = dd >> BBITS;
            unsigned p = atomicAdd(&lpos[b], 1u);
            rec[p] = ((dd & (BUCKET - 1)) << 20) | ss;
            bid[p] = (unsigned char)b;
        }
    __syncthreads();

    // phase 4: coalesced copy-out of contiguous runs
    for (int i = threadIdx.x; i < cnt; i += blockDim.x) {
        int b = bid[i];
        recs[gbase[b] + ((unsigned)i - start[b])] = rec[i];
    }
}

__global__ __launch_bounds__(512, 8)
void agg_kernel(const float* __restrict__ curh,
                const unsigned* __restrict__ recs,
                const unsigned* __restrict__ offsets,
                const unsigned* __restrict__ count,
                float* __restrict__ partials) {
    __shared__ float acc[BUCKET];   // 16 KB
    int b = blockIdx.x >> 2;
    int s = blockIdx.x & 3;
    for (int i = threadIdx.x; i < BUCKET; i += 512) acc[i] = 0.0f;
    __syncthreads();
    unsigned bs  = offsets[b];              // 16B-aligned
    unsigned cnt = count[b];
    unsigned quarter = (cnt >> 2) & ~3u;    // keep splits 16B-aligned
    unsigned ss = bs + (unsigned)s * quarter;
    unsigned sc = (s == 3) ? (cnt - 3u * quarter) : quarter;
    unsigned n4 = sc >> 2;
    const u32x4* rq = reinterpret_cast<const u32x4*>(recs + ss);
    unsigned q = threadIdx.x;
    for (; q + 512 < n4; q += 1024) {
        u32x4 r0 = __builtin_nontemporal_load(rq + q);
        u32x4 r1 = __builtin_nontemporal_load(rq + q + 512);
        float v0 = curh[r0.x & 0xFFFFFu];
        float v1 = curh[r0.y & 0xFFFFFu];
        float v2 = curh[r0.z & 0xFFFFFu];
        float v3 = curh[r0.w & 0xFFFFFu];
        float v4 = curh[r1.x & 0xFFFFFu];
        float v5 = curh[r1.y & 0xFFFFFu];
        float v6 = curh[r1.z & 0xFFFFFu];
        float v7 = curh[r1.w & 0xFFFFFu];
        atomicAdd(&acc[r0.x >> 20], v0);
        atomicAdd(&acc[r0.y >> 20], v1);
        atomicAdd(&acc[r0.z >> 20], v2);
        atomicAdd(&acc[r0.w >> 20], v3);
        atomicAdd(&acc[r1.x >> 20], v4);
        atomicAdd(&acc[r1.y >> 20], v5);
        atomicAdd(&acc[r1.z >> 20], v6);
        atomicAdd(&acc[r1.w >> 20], v7);
    }
    for (; q < n4; q += 512) {
        u32x4 r = __builtin_nontemporal_load(rq + q);
        float v0 = curh[r.x & 0xFFFFFu];
        float v1 = curh[r.y & 0xFFFFFu];
        float v2 = curh[r.z & 0xFFFFFu];
        float v3 = curh[r.w & 0xFFFFFu];
        atomicAdd(&acc[r.x >> 20], v0);
        atomicAdd(&acc[r.y >> 20], v1);
        atomicAdd(&acc[r.z >> 20], v2);
        atomicAdd(&acc[r.w >> 20], v3);
    }
    unsigned tb = ss + (n4 << 2);
    unsigned rem = sc & 3u;
    if (threadIdx.x < rem) {
        unsigned r = recs[tb + threadIdx.x];
        atomicAdd(&acc[r >> 20], curh[r & 0xFFFFFu]);
    }
    __syncthreads();
    float* outp = partials + ((size_t)blockIdx.x) * BUCKET;
    for (int i = threadIdx.x; i < BUCKET; i += 512)
        __builtin_nontemporal_store(acc[i], outp + i);
}

__global__ void reduce_combine(const float* __restrict__ curh,
                               const float* __restrict__ partials,
                               const float* __restrict__ w_self,
                               const float* __restrict__ w_neigh, int hop,
                               float* __restrict__ out, int n) {
    int i = blockIdx.x * blockDim.x + threadIdx.x;   // quad index
    int nq = (n + 3) >> 2;
    if (i >= nq) return;
    int node = i << 2;
    float wsv = w_self[hop], wnv = w_neigh[hop];
    int b = node >> BBITS, l = node & (BUCKET - 1);
    const float* p0 = partials + ((size_t)b * SPLIT) * BUCKET + l;
    if (node + 3 < n) {
        f32x4 a0 = __builtin_nontemporal_load(reinterpret_cast<const f32x4*>(p0));
        f32x4 a1 = __builtin_nontemporal_load(reinterpret_cast<const f32x4*>(p0 + BUCKET));
        f32x4 a2 = __builtin_nontemporal_load(reinterpret_cast<const f32x4*>(p0 + 2 * BUCKET));
        f32x4 a3 = __builtin_nontemporal_load(reinterpret_cast<const f32x4*>(p0 + 3 * BUCKET));
        f32x4 hh = *reinterpret_cast<const f32x4*>(curh + node);
        f32x4 o = hh * wsv + ((a0 + a1) + (a2 + a3)) * wnv;
        *reinterpret_cast<f32x4*>(out + node) = o;
    } else {
        for (int j = node; j < n; ++j) {
            int bb = j >> BBITS, ll = j & (BUCKET - 1);
            const float* pp = partials + ((size_t)bb * SPLIT) * BUCKET + ll;
            float sum = 0.0f;
            for (int k = 0; k < SPLIT; ++k) sum += pp[(size_t)k * BUCKET];
            out[j] = curh[j] * wsv + sum * wnv;
        }
    }
}

// ---------------- fallback (atomic path) ----------------

__global__ void zero_f32(float* __restrict__ p, int n) {
    int i = blockIdx.x * blockDim.x + threadIdx.x;
    if (i < n) p[i] = 0.0f;
}

__global__ void scatter_add(const float* __restrict__ h, const int* __restrict__ src,
                            const int* __restrict__ dst, float* __restrict__ neigh, int ne) {
    int i = blockIdx.x * blockDim.x + threadIdx.x;
    int base = i * 4;
    if (base + 3 < ne) {
        int4 s = *reinterpret_cast<const int4*>(src + base);
        int4 d = *reinterpret_cast<const int4*>(dst + base);
        atomicAdd(&neigh[d.x], h[s.x]);
        atomicAdd(&neigh[d.y], h[s.y]);
        atomicAdd(&neigh[d.z], h[s.z]);
        atomicAdd(&neigh[d.w], h[s.w]);
    } else if (base < ne) {
        for (int e = base; e < ne; ++e) atomicAdd(&neigh[dst[e]], h[src[e]]);
    }
}

__global__ void combine(const float* __restrict__ h, const float* __restrict__ neigh,
                        const float* __restrict__ w_self, const float* __restrict__ w_neigh,
                        int hop, float* __restrict__ out, int n) {
    int i = blockIdx.x * blockDim.x + threadIdx.x;
    if (i < n) out[i] = h[i] * w_self[hop] + neigh[i] * w_neigh[hop];
}

// ---------------- launch ----------------

extern "C" void kernel_launch(void* const* d_in, const int* in_sizes, int n_in,
                              void* d_out, int out_size, void* d_ws, size_t ws_size,
                              hipStream_t stream) {
    const float* h       = (const float*)d_in[0];
    const int*   src     = (const int*)d_in[1];
    const int*   dst     = (const int*)d_in[2];
    const float* w_self  = (const float*)d_in[3];
    const float* w_neigh = (const float*)d_in[4];
    float* out = (float*)d_out;

    const int n    = in_sizes[0];
    const int ne   = in_sizes[1];
    const int hops = in_sizes[3];

    const int nb = (n + BUCKET - 1) >> BBITS;

    size_t off = 0;
    auto take = [&](size_t bytes) { size_t o = off; off = (off + bytes + 255) & ~255UL; return o; };
    size_t o_recs     = take(((size_t)ne + 4 * NB_MAX) * 4);   // +alignment padding
    size_t o_count    = take((size_t)NB_MAX * 4);
    size_t o_offsets  = take((size_t)NB_MAX * 4);
    size_t o_cursor   = take((size_t)NB_MAX * 4);
    size_t o_partials = take((size_t)nb * SPLIT * BUCKET * 4);
    size_t o_buf      = take((size_t)n * 4);
    size_t needed = off;

    char* ws = (char*)d_ws;
    bool fast = (ws_size >= needed) && (nb <= NB_MAX) && (n <= (1 << 20));

    if (fast) {
        unsigned* recs     = (unsigned*)(ws + o_recs);
        unsigned* count    = (unsigned*)(ws + o_count);
        unsigned* offsets  = (unsigned*)(ws + o_offsets);
        unsigned* cursor   = (unsigned*)(ws + o_cursor);
        float*    partials = (float*)(ws + o_partials);
        float*    buf      = (float*)(ws + o_buf);

        zero_u32<<<1, NB_MAX, 0, stream>>>(count, NB_MAX);
        hist_kernel<<<HBLOCKS, BLK, 0, stream>>>(dst, ne, count, nb);
        scan_kernel<<<1, NB_MAX, 0, stream>>>(count, offsets, cursor, nb);
        bin_kernel<<<(ne + TILE - 1) / TILE, BLK, 0, stream>>>(src, dst, ne, cursor, recs);

        const int nq = (n + 3) >> 2;
        const int gridQ = (nq + BLK - 1) / BLK;
        const float* cur = h;
        for (int hop = 0; hop < hops; ++hop) {
            float* nxt = (hop == hops - 1) ? out : buf;
            agg_kernel<<<nb * SPLIT, 512, 0, stream>>>(cur, recs, offsets, count, partials);
            reduce_combine<<<gridQ, BLK, 0, stream>>>(cur, partials, w_self, w_neigh, hop, nxt, n);
            cur = nxt;
        }
    } else {
        float* buf   = (float*)d_ws;
        float* neigh = buf + n;
        const int gridN = (n + BLK - 1) / BLK;
        const int gridE = ((ne + 3) / 4 + BLK - 1) / BLK;
        const float* cur = h;
        for (int hop = 0; hop < hops; ++hop) {
            float* nxt = (hop == hops - 1) ? out : buf;
            zero_f32<<<gridN, BLK, 0, stream>>>(neigh, n);
            scatter_add<<<gridE, BLK, 0, stream>>>(cur, src, dst, neigh, ne);
            combine<<<gridN, BLK, 0, stream>>>(cur, neigh, w_self, w_neigh, hop, nxt, n);
            cur = nxt;
        }
    }
}